// Round 10
// baseline (238.274 us; speedup 1.0000x reference)
//
#include <hip/hip_runtime.h>
#include <hip/hip_bf16.h>

// Problem: B=8, N=4096, M=2048, IN=512, D=512, CTX=768
// out = h + attn @ f2,  attn = softmax(h W_a^T),  f2^T = W_out W_v G W_k^T,
// G = X^T X (symmetric), X = [h; h_retrieved W_c^T],  hr^T = W_c hret^T.

typedef unsigned short u16;
typedef __bf16 bf16x8 __attribute__((ext_vector_type(8)));
typedef float  f32x4  __attribute__((ext_vector_type(4)));
typedef float  f32v4  __attribute__((ext_vector_type(4)));
typedef u16    u16v4  __attribute__((ext_vector_type(4)));
typedef u16    u16v8  __attribute__((ext_vector_type(8)));

__device__ __forceinline__ u16 f2bf(float f) {
  unsigned u = __builtin_bit_cast(unsigned, f);
  u = u + 0x7FFFu + ((u >> 16) & 1u);   // RNE; inputs are finite
  return (u16)(u >> 16);
}
__device__ __forceinline__ float bf2f(u16 s) {
  return __builtin_bit_cast(float, (unsigned)s << 16);
}

// ---------------- elementwise f32 -> bf16 ----------------
__global__ __launch_bounds__(256) void cvt_f32_bf16(const float* __restrict__ in,
                                                    u16* __restrict__ out, long n) {
  long i = (((long)blockIdx.x * 256) + threadIdx.x) * 8;
  if (i >= n) return;
  f32v4 a = *(const f32v4*)(in + i);
  f32v4 b = *(const f32v4*)(in + i + 4);
  u16v8 o;
  o[0] = f2bf(a[0]); o[1] = f2bf(a[1]); o[2] = f2bf(a[2]); o[3] = f2bf(a[3]);
  o[4] = f2bf(b[0]); o[5] = f2bf(b[1]); o[6] = f2bf(b[2]); o[7] = f2bf(b[3]);
  *(u16v8*)(out + i) = o;
}

// ------- f32 -> bf16 transpose: xt[b][c][r] = bf16(h[b][r][c]) -------
__global__ __launch_bounds__(256) void cvt_T(const float* __restrict__ src,
                                             u16* __restrict__ dstT,
                                             long src_bs, long dstT_bs) {
  __shared__ u16 tile[64][72];
  long bz = blockIdx.z;
  const float* S = src + bz * src_bs;
  u16* DT = dstT + bz * dstT_bs;
  int r0 = blockIdx.x * 64;
  int c0 = blockIdx.y * 64;
  int t  = threadIdx.x;
  int tr = t >> 2;
  int tc = (t & 3) * 16;
  const float* sp = &S[(long)(r0 + tr) * 512 + c0 + tc];
#pragma unroll
  for (int q = 0; q < 2; ++q) {
    f32v4 a = *(const f32v4*)(sp + q * 8);
    f32v4 b = *(const f32v4*)(sp + q * 8 + 4);
    u16v8 o;
    o[0] = f2bf(a[0]); o[1] = f2bf(a[1]); o[2] = f2bf(a[2]); o[3] = f2bf(a[3]);
    o[4] = f2bf(b[0]); o[5] = f2bf(b[1]); o[6] = f2bf(b[2]); o[7] = f2bf(b[3]);
    *(u16v8*)&tile[tr][tc + q * 8] = o;
  }
  __syncthreads();
  int tr2 = t >> 3;
  int tc2 = (t & 7) * 8;
#pragma unroll
  for (int it = 0; it < 2; ++it) {
    int cr = it * 32 + tr2;
    u16v8 o;
#pragma unroll
    for (int j = 0; j < 8; ++j) o[j] = tile[tc2 + j][cr];
    *(u16v8*)&DT[(long)(c0 + cr) * 6144 + r0 + tc2] = o;
  }
}

// ------- all weight prep in ONE dispatch -------
__global__ __launch_bounds__(256) void prep_weights(
    const float* __restrict__ Wc, const float* __restrict__ Wa,
    const float* __restrict__ Wk, const float* __restrict__ Wv,
    const float* __restrict__ Wo,
    u16* __restrict__ wc, u16* __restrict__ wa, u16* __restrict__ wk,
    u16* __restrict__ wv, u16* __restrict__ wvT, u16* __restrict__ wo) {
  __shared__ u16 tile[64][72];
  int bx = blockIdx.x;
  int t = threadIdx.x;
  if (bx < 576) {
    const float* src; u16* dst; long base;
    if (bx < 192)      { src = Wc; dst = wc; base = (long)bx * 2048; }
    else if (bx < 320) { src = Wa; dst = wa; base = (long)(bx - 192) * 2048; }
    else if (bx < 448) { src = Wk; dst = wk; base = (long)(bx - 320) * 2048; }
    else               { src = Wo; dst = wo; base = (long)(bx - 448) * 2048; }
    long i = base + (long)t * 8;
    f32v4 a = *(const f32v4*)(src + i);
    f32v4 b = *(const f32v4*)(src + i + 4);
    u16v8 o;
    o[0] = f2bf(a[0]); o[1] = f2bf(a[1]); o[2] = f2bf(a[2]); o[3] = f2bf(a[3]);
    o[4] = f2bf(b[0]); o[5] = f2bf(b[1]); o[6] = f2bf(b[2]); o[7] = f2bf(b[3]);
    *(u16v8*)(dst + i) = o;
  } else {
    int b2 = bx - 576;
    int r0 = (b2 >> 3) * 64, c0 = (b2 & 7) * 64;
    int tr = t >> 2, tc = (t & 3) * 16;
    const float* sp = &Wv[(long)(r0 + tr) * 512 + c0 + tc];
#pragma unroll
    for (int q = 0; q < 2; ++q) {
      f32v4 a = *(const f32v4*)(sp + q * 8);
      f32v4 b = *(const f32v4*)(sp + q * 8 + 4);
      u16v8 o;
      o[0] = f2bf(a[0]); o[1] = f2bf(a[1]); o[2] = f2bf(a[2]); o[3] = f2bf(a[3]);
      o[4] = f2bf(b[0]); o[5] = f2bf(b[1]); o[6] = f2bf(b[2]); o[7] = f2bf(b[3]);
      *(u16v8*)&wv[(long)(r0 + tr) * 512 + c0 + tc + q * 8] = o;
      *(u16v8*)&tile[tr][tc + q * 8] = o;
    }
    __syncthreads();
    int tr2 = t >> 3, tc2 = (t & 7) * 8;
#pragma unroll
    for (int it = 0; it < 2; ++it) {
      int cr = it * 32 + tr2;
      u16v8 o;
#pragma unroll
      for (int j = 0; j < 8; ++j) o[j] = tile[tc2 + j][cr];
      *(u16v8*)&wvT[(long)(c0 + cr) * 512 + r0 + tc2] = o;
    }
  }
}

// -------- reduce 8 split-K bf16 slices -> bf16 (per batch 512x512) --------
__global__ __launch_bounds__(256) void reduce8_bf16(const u16* __restrict__ parts,
                                                    u16* __restrict__ out) {
  long i = (((long)blockIdx.x * 256) + threadIdx.x) * 8;
  long b = i >> 18;
  long r = i & 262143;
  const u16* p = parts + b * 2097152 + r;
  float acc[8] = {};
#pragma unroll
  for (int s = 0; s < 8; ++s) {
    u16v8 v = *(const u16v8*)(p + (long)s * 262144);
#pragma unroll
    for (int j = 0; j < 8; ++j) acc[j] += bf2f(v[j]);
  }
  u16v8 o;
#pragma unroll
  for (int j = 0; j < 8; ++j) o[j] = f2bf(acc[j]);
  *(u16v8*)(out + i) = o;
}

// ====== NT GEMM 128x128, TRIPLE-buffered, 1 barrier/tile, counted vmcnt ======
// Per tile: {vmcnt(8|0); s_barrier; issue 8 stages for tile kt+2; 16 MFMA}.
// Prefetch depth = 2 tiles (~1100 cy cover >= HBM latency). LDS 96KB -> 1 blk/CU.
// Buffers: A buf i @ i*16384, B buf i @ 49152 + i*16384 (bytes).
// Race ledger: barrier at kt top ends all reads of buf (kt-1)%3 == (kt+2)%3 before
// its restage; vmcnt(8) drains stage(kt) (oldest 8) leaving stage(kt+1) in flight;
// __syncthreads before epilogue (scratch aliases buf A0/A1).
// MODE: 0 = bf16 store, 1 = f32 store + f32 residual add.
template <int MODE>
__global__ __launch_bounds__(256) void gemm_nt(
    const u16* __restrict__ A, const u16* __restrict__ B, void* __restrict__ Cout,
    const float* __restrict__ Res, int K, int lda, int ldb, int ldc,
    long sA, long sB, long sC, long sS, long sRes, int kslices) {
  __shared__ __align__(16) char smem_c[98304];

  int gx = gridDim.x, gy = gridDim.y;
  int nwg = gx * gy * (int)gridDim.z;
  int flat = blockIdx.x + gx * (blockIdx.y + gy * blockIdx.z);
  if ((nwg & 7) == 0) { int q = nwg >> 3; flat = (flat & 7) * q + (flat >> 3); }
  int bx = flat % gx; int tmp = flat / gx; int by = tmp % gy; int z = tmp / gy;

  int b = z / kslices;
  int s = z - b * kslices;
  const u16* Ag = A + (long)b * sA + (long)s * K;
  const u16* Bg = B + (long)b * sB + (long)s * K;

  long m0 = (long)bx * 128;
  long n0 = (long)by * 128;

  int tid  = threadIdx.x;
  int lane = tid & 63;
  int wid  = tid >> 6;
  int wm = wid >> 1, wn = wid & 1;

  int srow = wid * 8 + (lane >> 3);
  int scol = (lane & 7) * 8;

  auto stageA = [&](int buf, int k0) {
    u16* Asd = (u16*)(smem_c + buf * 16384);
#pragma unroll
    for (int c = 0; c < 4; ++c) {
      int row = c * 32 + srow;
      __builtin_amdgcn_global_load_lds(
          (const __attribute__((address_space(1))) void*)(Ag + (m0 + row) * lda + k0 + scol),
          (__attribute__((address_space(3))) void*)(Asd + (c * 32 + wid * 8) * 64),
          16, 0, 0);
    }
  };
  auto stageB = [&](int buf, int k0) {
    u16* Bsd = (u16*)(smem_c + 49152 + buf * 16384);
#pragma unroll
    for (int c = 0; c < 4; ++c) {
      int row = c * 32 + srow;
      __builtin_amdgcn_global_load_lds(
          (const __attribute__((address_space(1))) void*)(Bg + (n0 + row) * ldb + k0 + scol),
          (__attribute__((address_space(3))) void*)(Bsd + (c * 32 + wid * 8) * 64),
          16, 0, 0);
    }
  };

  f32x4 acc[4][4] = {};
  int nk = K >> 6;

  // prologue: stage tiles 0 and 1
  stageA(0, 0); stageB(0, 0);
  if (nk > 1) { stageA(1, 64); stageB(1, 64); }

  int cur = 0;
  for (int kt = 0; kt < nk; ++kt) {
    if (kt + 1 < nk) {
      asm volatile("s_waitcnt vmcnt(8)\n\ts_barrier" ::: "memory");
    } else {
      asm volatile("s_waitcnt vmcnt(0)\n\ts_barrier" ::: "memory");
    }
    if (kt + 2 < nk) {
      int tgt = cur + 2; if (tgt >= 3) tgt -= 3;
      stageA(tgt, (kt + 2) * 64);
      stageB(tgt, (kt + 2) * 64);
    }
    const u16* Asc = (const u16*)(smem_c + cur * 16384);
    const u16* Bsc = (const u16*)(smem_c + 49152 + cur * 16384);
#pragma unroll
    for (int kk = 0; kk < 2; ++kk) {
      int kofs = kk * 32 + (lane >> 4) * 8;
      bf16x8 af[4], bfr[4];
#pragma unroll
      for (int i = 0; i < 4; ++i) {
        af[i]  = *(const bf16x8*)&Asc[(wm * 64 + i * 16 + (lane & 15)) * 64 + kofs];
        bfr[i] = *(const bf16x8*)&Bsc[(wn * 64 + i * 16 + (lane & 15)) * 64 + kofs];
      }
#pragma unroll
      for (int i = 0; i < 4; ++i)
#pragma unroll
        for (int j = 0; j < 4; ++j)
          acc[i][j] = __builtin_amdgcn_mfma_f32_16x16x32_bf16(af[i], bfr[j], acc[i][j], 0, 0, 0);
    }
    ++cur; if (cur >= 3) cur = 0;
  }

  __syncthreads();   // epilogue scratch aliases buffers; all reads must be done

  float* ep = (float*)(smem_c + wid * 4608);
  long cb  = (long)b * sC + (long)s * sS;
  int row0 = (int)m0 + wm * 64;
  int colb = (int)n0 + wn * 64;
  int lq = lane >> 4;
  int lr = lane & 15;

#pragma unroll
  for (int i = 0; i < 4; ++i) {
#pragma unroll
    for (int j = 0; j < 4; ++j)
#pragma unroll
      for (int r = 0; r < 4; ++r)
        ep[(lq * 4 + r) * 72 + lr + j * 16] = acc[i][j][r];
#pragma unroll
    for (int p = 0; p < 4; ++p) {
      int rl = p * 4 + lq;
      f32x4 v = *(f32x4*)&ep[rl * 72 + lr * 4];
      long off = (long)(row0 + i * 16 + rl) * ldc + colb + lr * 4;
      if (MODE == 0) {
        u16v4 o;
#pragma unroll
        for (int t2 = 0; t2 < 4; ++t2) o[t2] = f2bf(v[t2]);
        *(u16v4*)((u16*)Cout + cb + off) = o;
      } else {
        const float* R = Res + (long)b * sRes;
        f32v4 rv = *(const f32v4*)&R[off];
        f32v4 ov;
#pragma unroll
        for (int t2 = 0; t2 < 4; ++t2) ov[t2] = v[t2] + rv[t2];
        *(f32v4*)((float*)Cout + cb + off) = ov;
      }
    }
  }
}

// ------------- NT GEMM 64x128 (small GEMMs only) -------------
__global__ __launch_bounds__(256) void gemm64(
    const u16* __restrict__ A, const u16* __restrict__ B, u16* __restrict__ Cout,
    int K, int lda, int ldb, int ldc, long sA, long sB, long sC) {
  __shared__ __align__(16) char smem_c[49152];

  int gx = gridDim.x, gy = gridDim.y;
  int nwg = gx * gy * (int)gridDim.z;
  int flat = blockIdx.x + gx * (blockIdx.y + gy * blockIdx.z);
  if ((nwg & 7) == 0) { int q = nwg >> 3; flat = (flat & 7) * q + (flat >> 3); }
  int bx = flat % gx; int tmp = flat / gx; int by = tmp % gy; int b = tmp / gy;

  long n0 = (long)bx * 128;
  long m0 = (long)by * 64;
  const u16* Ag = A + (long)b * sA;
  const u16* Bg = B + (long)b * sB;

  int tid  = threadIdx.x;
  int lane = tid & 63;
  int wid  = tid >> 6;
  int wm = wid >> 1, wn = wid & 1;

  int srow = wid * 8 + (lane >> 3);
  int scol = (lane & 7) * 8;

  auto stageA = [&](u16* Asd, int k0) {
#pragma unroll
    for (int c = 0; c < 2; ++c) {
      int row = c * 32 + srow;
      __builtin_amdgcn_global_load_lds(
          (const __attribute__((address_space(1))) void*)(Ag + (m0 + row) * lda + k0 + scol),
          (__attribute__((address_space(3))) void*)(Asd + (c * 32 + wid * 8) * 64),
          16, 0, 0);
    }
  };
  auto stageB = [&](u16* Bsd, int k0) {
#pragma unroll
    for (int c = 0; c < 4; ++c) {
      int row = c * 32 + srow;
      __builtin_amdgcn_global_load_lds(
          (const __attribute__((address_space(1))) void*)(Bg + (n0 + row) * ldb + k0 + scol),
          (__attribute__((address_space(3))) void*)(Bsd + (c * 32 + wid * 8) * 64),
          16, 0, 0);
    }
  };

  f32x4 acc[2][4] = {};
  int nk = K >> 6;

  stageA((u16*)smem_c, 0);
  stageB((u16*)(smem_c + 16384), 0);

  for (int t = 0; t < nk; ++t) {
    u16* Asc = (u16*)(smem_c + (t & 1) * 8192);
    u16* Bsc = (u16*)(smem_c + 16384 + (t & 1) * 16384);
    u16* Asn = (u16*)(smem_c + ((t + 1) & 1) * 8192);
    u16* Bsn = (u16*)(smem_c + 16384 + ((t + 1) & 1) * 16384);
    bool more = (t + 1) < nk;
    if (more) {
      stageA(Asn, (t + 1) * 64);
      stageB(Bsn, (t + 1) * 64);
      asm volatile("s_waitcnt vmcnt(6)\n\ts_barrier" ::: "memory");
    } else {
      asm volatile("s_waitcnt vmcnt(0)\n\ts_barrier" ::: "memory");
    }
#pragma unroll
    for (int kk = 0; kk < 2; ++kk) {
      int kofs = kk * 32 + (lane >> 4) * 8;
      bf16x8 af[2], bfr[4];
#pragma unroll
      for (int i = 0; i < 2; ++i)
        af[i]  = *(const bf16x8*)&Asc[(wm * 32 + i * 16 + (lane & 15)) * 64 + kofs];
#pragma unroll
      for (int j = 0; j < 4; ++j)
        bfr[j] = *(const bf16x8*)&Bsc[(wn * 64 + j * 16 + (lane & 15)) * 64 + kofs];
#pragma unroll
      for (int i = 0; i < 2; ++i)
#pragma unroll
        for (int j = 0; j < 4; ++j)
          acc[i][j] = __builtin_amdgcn_mfma_f32_16x16x32_bf16(af[i], bfr[j], acc[i][j], 0, 0, 0);
    }
    asm volatile("s_barrier" ::: "memory");
  }

  int lq = lane >> 4;
  int lr = lane & 15;
  float* ep = (float*)(smem_c + wid * 4608);
  long cb  = (long)b * sC;
  int row0 = (int)m0 + wm * 32;
  int colb = (int)n0 + wn * 64;
#pragma unroll
  for (int i = 0; i < 2; ++i) {
#pragma unroll
    for (int j = 0; j < 4; ++j)
#pragma unroll
      for (int r = 0; r < 4; ++r)
        ep[(lq * 4 + r) * 72 + lr + j * 16] = acc[i][j][r];
#pragma unroll
    for (int p = 0; p < 4; ++p) {
      int rl = p * 4 + lq;
      f32x4 v = *(f32x4*)&ep[rl * 72 + lr * 4];
      long off = (long)(row0 + i * 16 + rl) * ldc + colb + lr * 4;
      u16v4 o;
#pragma unroll
      for (int t2 = 0; t2 < 4; ++t2) o[t2] = f2bf(v[t2]);
      *(u16v4*)(Cout + cb + off) = o;
    }
  }
}

// ------- logits GEMM with FUSED channel softmax, f32 A (reads h directly) -------
__global__ __launch_bounds__(256, 2) void gemm_sm(
    const float* __restrict__ A,  // [32768 x 512] f32 (h)
    const u16* __restrict__ Bw,   // [512 x 512] bf16 (w_attn)
    u16* __restrict__ C) {        // [32768 x 512] bf16 attn
  __shared__ __align__(16) char smem[73728];
  u16* As = (u16*)smem;                 // [64][64]
  u16* Bs = (u16*)(smem + 8192);        // [512][64]

  int nwg = gridDim.x;
  int flat = blockIdx.x;
  if ((nwg & 7) == 0) { int q = nwg >> 3; flat = (flat & 7) * q + (flat >> 3); }
  long m0 = (long)flat * 64;

  int tid = threadIdx.x;
  int lane = tid & 63;
  int wid = tid >> 6;

  int srow = wid * 8 + (lane >> 3);
  int scol = (lane & 7) * 8;
  int arow  = tid >> 2;
  int acolb = (tid & 3) * 16;

  f32x4 acc[4][8] = {};

  for (int k0 = 0; k0 < 512; k0 += 64) {
    const float* sp = A + (m0 + arow) * 512 + k0 + acolb;
    f32v4 x0 = *(const f32v4*)sp;
    f32v4 x1 = *(const f32v4*)(sp + 4);
    f32v4 x2 = *(const f32v4*)(sp + 8);
    f32v4 x3 = *(const f32v4*)(sp + 12);
#pragma unroll
    for (int c = 0; c < 16; ++c) {
      int row = c * 32 + srow;
      __builtin_amdgcn_global_load_lds(
          (const __attribute__((address_space(1))) void*)(Bw + (long)row * 512 + k0 + scol),
          (__attribute__((address_space(3))) void*)(Bs + (c * 32 + wid * 8) * 64),
          16, 0, 0);
    }
    u16v8 o0, o1;
    o0[0] = f2bf(x0[0]); o0[1] = f2bf(x0[1]); o0[2] = f2bf(x0[2]); o0[3] = f2bf(x0[3]);
    o0[4] = f2bf(x1[0]); o0[5] = f2bf(x1[1]); o0[6] = f2bf(x1[2]); o0[7] = f2bf(x1[3]);
    o1[0] = f2bf(x2[0]); o1[1] = f2bf(x2[1]); o1[2] = f2bf(x2[2]); o1[3] = f2bf(x2[3]);
    o1[4] = f2bf(x3[0]); o1[5] = f2bf(x3[1]); o1[6] = f2bf(x3[2]); o1[7] = f2bf(x3[3]);
    *(u16v8*)&As[arow * 64 + acolb] = o0;
    *(u16v8*)&As[arow * 64 + acolb + 8] = o1;
    __syncthreads();
#pragma unroll
    for (int kk = 0; kk < 2; ++kk) {
      int kofs = kk * 32 + (lane >> 4) * 8;
      bf16x8 af[4], bfr[8];
#pragma unroll
      for (int i = 0; i < 4; ++i)
        af[i] = *(const bf16x8*)&As[(i * 16 + (lane & 15)) * 64 + kofs];
#pragma unroll
      for (int j = 0; j < 8; ++j)
        bfr[j] = *(const bf16x8*)&Bs[(wid * 128 + j * 16 + (lane & 15)) * 64 + kofs];
#pragma unroll
      for (int i = 0; i < 4; ++i)
#pragma unroll
        for (int j = 0; j < 8; ++j)
          acc[i][j] = __builtin_amdgcn_mfma_f32_16x16x32_bf16(af[i], bfr[j], acc[i][j], 0, 0, 0);
    }
    __syncthreads();
  }

  int lq = lane >> 4, lr = lane & 15;
  float* sm = (float*)smem;            // [64][4]
  float* ss = (float*)(smem + 1024);   // [64][4]

#pragma unroll
  for (int i = 0; i < 4; ++i)
#pragma unroll
    for (int r = 0; r < 4; ++r) {
      float m = acc[i][0][r];
#pragma unroll
      for (int j = 1; j < 8; ++j) m = fmaxf(m, acc[i][j][r]);
#pragma unroll
      for (int o = 1; o < 16; o <<= 1) m = fmaxf(m, __shfl_xor(m, o, 16));
      if (lr == 0) sm[(i * 16 + lq * 4 + r) * 4 + wid] = m;
    }
  __syncthreads();
  float rinv[4][4];
#pragma unroll
  for (int i = 0; i < 4; ++i)
#pragma unroll
    for (int r = 0; r < 4; ++r) {
      f32v4 g4 = *(const f32v4*)&sm[(i * 16 + lq * 4 + r) * 4];
      float gm = fmaxf(fmaxf(g4[0], g4[1]), fmaxf(g4[2], g4[3]));
      float s = 0.f;
#pragma unroll
      for (int j = 0; j < 8; ++j) {
        float e = __expf(acc[i][j][r] - gm);
        acc[i][j][r] = e;
        s += e;
      }
#pragma unroll
      for (int o = 1; o < 16; o <<= 1) s += __shfl_xor(s, o, 16);
      if (lr == 0) ss[(i * 16 + lq * 4 + r) * 4 + wid] = s;
    }
  __syncthreads();
#pragma unroll
  for (int i = 0; i < 4; ++i)
#pragma unroll
    for (int r = 0; r < 4; ++r) {
      f32v4 g4 = *(const f32v4*)&ss[(i * 16 + lq * 4 + r) * 4];
      rinv[i][r] = 1.0f / (g4[0] + g4[1] + g4[2] + g4[3]);
    }
  __syncthreads();

  float* ep = (float*)(smem + wid * 4608);
#pragma unroll
  for (int i = 0; i < 4; ++i) {
#pragma unroll
    for (int jh = 0; jh < 2; ++jh) {
#pragma unroll
      for (int j = 0; j < 4; ++j)
#pragma unroll
        for (int r = 0; r < 4; ++r)
          ep[(lq * 4 + r) * 72 + lr + j * 16] = acc[i][jh * 4 + j][r] * rinv[i][r];
#pragma unroll
      for (int p = 0; p < 4; ++p) {
        int rl = p * 4 + lq;
        f32x4 v = *(f32x4*)&ep[rl * 72 + lr * 4];
        u16v4 o;
#pragma unroll
        for (int t = 0; t < 4; ++t) o[t] = f2bf(v[t]);
        *(u16v4*)&C[(m0 + i * 16 + rl) * 512 + wid * 128 + jh * 64 + lr * 4] = o;
      }
    }
  }
}

// ---------------- host ----------------
extern "C" void kernel_launch(void* const* d_in, const int* in_sizes, int n_in,
                              void* d_out, int out_size, void* d_ws, size_t ws_size,
                              hipStream_t stream) {
  (void)in_sizes; (void)n_in; (void)out_size; (void)ws_size;
  const float* h    = (const float*)d_in[0];
  const float* hret = (const float*)d_in[1];
  const float* Wc   = (const float*)d_in[2];
  const float* Wa   = (const float*)d_in[3];
  const float* Wk   = (const float*)d_in[4];
  const float* Wv   = (const float*)d_in[5];
  const float* Wo   = (const float*)d_in[6];
  float* out = (float*)d_out;
  char*  ws  = (char*)d_ws;

  constexpr long MB = 1024 * 1024;
  // workspace: weights 0..4MB; hret_bf 4..28 (dead before Gram writes gparts);
  // gparts 4..36; attn 36..68; g_bf 68; u 72; v1 73; f2t 77; xt 84..132.
  u16*   w_cond  = (u16*)(ws + 0);
  u16*   w_attn  = (u16*)(ws + 786432);
  u16*   w_k     = (u16*)(ws + 1310720);
  u16*   w_v     = (u16*)(ws + 1835008);
  u16*   w_out   = (u16*)(ws + 2359296);
  u16*   w_vT    = (u16*)(ws + 2883584);
  u16*   hret_bf = (u16*)(ws + 4 * MB);
  u16*   gparts  = (u16*)(ws + 4 * MB);   // overlay hret_bf (dead before Gram)
  u16*   attn    = (u16*)(ws + 36 * MB);
  u16*   g_bf    = (u16*)(ws + 68 * MB);
  u16*   u_mat   = (u16*)(ws + 72 * MB);
  u16*   v1      = (u16*)(ws + 73 * MB);
  u16*   f2t     = (u16*)(ws + 77 * MB);
  u16*   xt      = (u16*)(ws + 84 * MB);

  // 1) xt[:, 0:4096] = h^T (f32 read, bf16 transposed write)
  cvt_T<<<dim3(64, 8, 8), 256, 0, stream>>>(h, xt, 2097152L, 3145728L);
  // 2) all weights in one dispatch
  prep_weights<<<640, 256, 0, stream>>>(Wc, Wa, Wk, Wv, Wo,
      w_cond, w_attn, w_k, w_v, w_vT, w_out);
  // 3) hret -> bf16 (plain layout)
  cvt_f32_bf16<<<6144, 256, 0, stream>>>(hret, hret_bf, 12582912L);

  // 4) hr^T = W_c @ hret^T  == NT(w_cond, hret_bf), normal store into xt[:, 4096:6144]
  //    M=512 (d), N=2048 (n), K=768; A shared across batches.
  gemm_nt<0><<<dim3(4, 16, 8), 256, 0, stream>>>(w_cond, hret_bf, xt + 4096, nullptr,
      768, 768, 768, 6144, 0, 1572864L, 3145728L, 0, 0, 1);

  // 5) attn = softmax(h @ W_attn^T) fused, reads h f32 directly (M=32768 flat)
  gemm_sm<<<512, 256, 0, stream>>>(h, w_attn, attn);

  // 6) Gram G = X^T X via NT(xt, xt), split-K=8 bf16 partials, reduce -> bf16
  gemm_nt<0><<<dim3(4, 4, 64), 256, 0, stream>>>(xt, xt, gparts, nullptr,
      768, 6144, 6144, 512, 3145728L, 3145728L, 2097152L, 262144L, 0, 8);
  reduce8_bf16<<<1024, 256, 0, stream>>>(gparts, g_bf);

  // 7) f2^T = W_out W_v G W_k^T (G symmetric):
  gemm64<<<dim3(4, 8, 1), 256, 0, stream>>>(w_out, w_vT, u_mat,
      512, 512, 512, 512, 0, 0, 0);
  gemm64<<<dim3(4, 8, 8), 256, 0, stream>>>(u_mat, g_bf, v1,
      512, 512, 512, 512, 0, 262144L, 262144L);
  gemm64<<<dim3(4, 8, 8), 256, 0, stream>>>(v1, w_k, f2t,
      512, 512, 512, 512, 262144L, 0, 262144L);

  // 8) out = h + attn @ f2  (128^2 triple-buffered, fused residual, f32 out)
  gemm_nt<1><<<dim3(32, 4, 8), 256, 0, stream>>>(attn, f2t, out, h,
      512, 512, 512, 512, 2097152L, 262144L, 2097152L, 0, 2097152L, 1);
}

// Round 11
// 197.184 us; speedup vs baseline: 1.2084x; 1.2084x over previous
//
#include <hip/hip_runtime.h>
#include <hip/hip_bf16.h>

// Problem: B=8, N=4096, M=2048, IN=512, D=512, CTX=768
// out = h + attn @ f2,  attn = softmax(h W_a^T),  f2^T = W_out W_v G W_k^T,
// G = X^T X (symmetric), X = [h; h_retrieved W_c^T],  hr^T = W_c hret^T.

typedef unsigned short u16;
typedef __bf16 bf16x8 __attribute__((ext_vector_type(8)));
typedef float  f32x4  __attribute__((ext_vector_type(4)));
typedef float  f32v4  __attribute__((ext_vector_type(4)));
typedef u16    u16v4  __attribute__((ext_vector_type(4)));
typedef u16    u16v8  __attribute__((ext_vector_type(8)));

__device__ __forceinline__ u16 f2bf(float f) {
  unsigned u = __builtin_bit_cast(unsigned, f);
  u = u + 0x7FFFu + ((u >> 16) & 1u);   // RNE; inputs are finite
  return (u16)(u >> 16);
}
__device__ __forceinline__ float bf2f(u16 s) {
  return __builtin_bit_cast(float, (unsigned)s << 16);
}

// ---------------- elementwise f32 -> bf16 ----------------
__global__ __launch_bounds__(256) void cvt_f32_bf16(const float* __restrict__ in,
                                                    u16* __restrict__ out, long n) {
  long i = (((long)blockIdx.x * 256) + threadIdx.x) * 8;
  if (i >= n) return;
  f32v4 a = *(const f32v4*)(in + i);
  f32v4 b = *(const f32v4*)(in + i + 4);
  u16v8 o;
  o[0] = f2bf(a[0]); o[1] = f2bf(a[1]); o[2] = f2bf(a[2]); o[3] = f2bf(a[3]);
  o[4] = f2bf(b[0]); o[5] = f2bf(b[1]); o[6] = f2bf(b[2]); o[7] = f2bf(b[3]);
  *(u16v8*)(out + i) = o;
}

// ------- f32 -> bf16 transpose: xt[b][c][r] = bf16(h[b][r][c]) -------
__global__ __launch_bounds__(256) void cvt_T(const float* __restrict__ src,
                                             u16* __restrict__ dstT,
                                             long src_bs, long dstT_bs) {
  __shared__ u16 tile[64][72];
  long bz = blockIdx.z;
  const float* S = src + bz * src_bs;
  u16* DT = dstT + bz * dstT_bs;
  int r0 = blockIdx.x * 64;
  int c0 = blockIdx.y * 64;
  int t  = threadIdx.x;
  int tr = t >> 2;
  int tc = (t & 3) * 16;
  const float* sp = &S[(long)(r0 + tr) * 512 + c0 + tc];
#pragma unroll
  for (int q = 0; q < 2; ++q) {
    f32v4 a = *(const f32v4*)(sp + q * 8);
    f32v4 b = *(const f32v4*)(sp + q * 8 + 4);
    u16v8 o;
    o[0] = f2bf(a[0]); o[1] = f2bf(a[1]); o[2] = f2bf(a[2]); o[3] = f2bf(a[3]);
    o[4] = f2bf(b[0]); o[5] = f2bf(b[1]); o[6] = f2bf(b[2]); o[7] = f2bf(b[3]);
    *(u16v8*)&tile[tr][tc + q * 8] = o;
  }
  __syncthreads();
  int tr2 = t >> 3;
  int tc2 = (t & 7) * 8;
#pragma unroll
  for (int it = 0; it < 2; ++it) {
    int cr = it * 32 + tr2;
    u16v8 o;
#pragma unroll
    for (int j = 0; j < 8; ++j) o[j] = tile[tc2 + j][cr];
    *(u16v8*)&DT[(long)(c0 + cr) * 6144 + r0 + tc2] = o;
  }
}

// ------- all weight prep in ONE dispatch -------
__global__ __launch_bounds__(256) void prep_weights(
    const float* __restrict__ Wc, const float* __restrict__ Wa,
    const float* __restrict__ Wk, const float* __restrict__ Wv,
    const float* __restrict__ Wo,
    u16* __restrict__ wc, u16* __restrict__ wa, u16* __restrict__ wk,
    u16* __restrict__ wv, u16* __restrict__ wvT, u16* __restrict__ wo) {
  __shared__ u16 tile[64][72];
  int bx = blockIdx.x;
  int t = threadIdx.x;
  if (bx < 576) {
    const float* src; u16* dst; long base;
    if (bx < 192)      { src = Wc; dst = wc; base = (long)bx * 2048; }
    else if (bx < 320) { src = Wa; dst = wa; base = (long)(bx - 192) * 2048; }
    else if (bx < 448) { src = Wk; dst = wk; base = (long)(bx - 320) * 2048; }
    else               { src = Wo; dst = wo; base = (long)(bx - 448) * 2048; }
    long i = base + (long)t * 8;
    f32v4 a = *(const f32v4*)(src + i);
    f32v4 b = *(const f32v4*)(src + i + 4);
    u16v8 o;
    o[0] = f2bf(a[0]); o[1] = f2bf(a[1]); o[2] = f2bf(a[2]); o[3] = f2bf(a[3]);
    o[4] = f2bf(b[0]); o[5] = f2bf(b[1]); o[6] = f2bf(b[2]); o[7] = f2bf(b[3]);
    *(u16v8*)(dst + i) = o;
  } else {
    int b2 = bx - 576;
    int r0 = (b2 >> 3) * 64, c0 = (b2 & 7) * 64;
    int tr = t >> 2, tc = (t & 3) * 16;
    const float* sp = &Wv[(long)(r0 + tr) * 512 + c0 + tc];
#pragma unroll
    for (int q = 0; q < 2; ++q) {
      f32v4 a = *(const f32v4*)(sp + q * 8);
      f32v4 b = *(const f32v4*)(sp + q * 8 + 4);
      u16v8 o;
      o[0] = f2bf(a[0]); o[1] = f2bf(a[1]); o[2] = f2bf(a[2]); o[3] = f2bf(a[3]);
      o[4] = f2bf(b[0]); o[5] = f2bf(b[1]); o[6] = f2bf(b[2]); o[7] = f2bf(b[3]);
      *(u16v8*)&wv[(long)(r0 + tr) * 512 + c0 + tc + q * 8] = o;
      *(u16v8*)&tile[tr][tc + q * 8] = o;
    }
    __syncthreads();
    int tr2 = t >> 3, tc2 = (t & 7) * 8;
#pragma unroll
    for (int it = 0; it < 2; ++it) {
      int cr = it * 32 + tr2;
      u16v8 o;
#pragma unroll
      for (int j = 0; j < 8; ++j) o[j] = tile[tc2 + j][cr];
      *(u16v8*)&wvT[(long)(c0 + cr) * 512 + r0 + tc2] = o;
    }
  }
}

// -------- reduce 8 split-K bf16 slices -> bf16 (per batch 512x512) --------
__global__ __launch_bounds__(256) void reduce8_bf16(const u16* __restrict__ parts,
                                                    u16* __restrict__ out) {
  long i = (((long)blockIdx.x * 256) + threadIdx.x) * 8;
  long b = i >> 18;
  long r = i & 262143;
  const u16* p = parts + b * 2097152 + r;
  float acc[8] = {};
#pragma unroll
  for (int s = 0; s < 8; ++s) {
    u16v8 v = *(const u16v8*)(p + (long)s * 262144);
#pragma unroll
    for (int j = 0; j < 8; ++j) acc[j] += bf2f(v[j]);
  }
  u16v8 o;
#pragma unroll
  for (int j = 0; j < 8; ++j) o[j] = f2bf(acc[j]);
  *(u16v8*)(out + i) = o;
}

// ============ 256x256 multi-phase GEMM (R9 version, measured) ============
// 512 threads = 8 waves (2M x 4N). BK=64. LDS 128KB. Swizzled staging + reads.
// MODE: 0 = bf16 store, 1 = f32 store + f32 residual.
template <int MODE>
__global__ __launch_bounds__(512, 2) void gemm256(
    const u16* __restrict__ A, const u16* __restrict__ B, void* __restrict__ Cout,
    const float* __restrict__ Res, int K, int lda, int ldb, int ldc,
    long sA, long sB, long sC, long sS, long sRes, int kslices) {
  __shared__ __align__(16) u16 lds[65536];   // 128 KB

  int gx = gridDim.x, gy = gridDim.y;
  int nwg = gx * gy * (int)gridDim.z;
  int flat = blockIdx.x + gx * (blockIdx.y + gy * blockIdx.z);
  if ((nwg & 7) == 0) { int q = nwg >> 3; flat = (flat & 7) * q + (flat >> 3); }
  int bx = flat % gx; int tmp = flat / gx; int by = tmp % gy; int z = tmp / gy;
  int b = z / kslices;
  int s = z - b * kslices;

  long m0 = (long)bx * 256;
  long n0 = (long)by * 256;
  const u16* Ag = A + (long)b * sA + (long)s * K;
  const u16* Bg = B + (long)b * sB + (long)s * K;

  int tid  = threadIdx.x;
  int lane = tid & 63;
  int wid  = tid >> 6;        // 0..7
  int wm = wid >> 2;          // 0..1  (M half)
  int wn = wid & 3;           // 0..3  (N quarter)
  int l15 = lane & 15, l16 = lane >> 4, l7 = lane & 7;

  auto stage_half = [&](bool isA, int buf, int h, int ktile) {
    const u16* G = isA ? Ag : Bg;
    long rb = (isA ? m0 : n0) + h * 128;
    int ldg = isA ? lda : ldb;
    u16* base = lds + (isA ? 0 : 32768) + buf * 16384 + h * 8192;
    int row_lo = wid * 8 + (lane >> 3);
    int ce = ((lane & 7) ^ ((lane >> 3) & 7)) * 8;
#pragma unroll
    for (int q = 0; q < 2; ++q) {
      const u16* src = G + (rb + q * 64 + row_lo) * (long)ldg + ktile * 64 + ce;
      u16* dst = base + (q * 512 + wid * 64) * 8;
      __builtin_amdgcn_global_load_lds(
          (const __attribute__((address_space(1))) void*)src,
          (__attribute__((address_space(3))) void*)dst, 16, 0, 0);
    }
  };

  f32x4 acc[8][4] = {};
  int nk = K >> 6;

  stage_half(true,  0, 0, 0); stage_half(true,  0, 1, 0);
  stage_half(false, 0, 0, 0); stage_half(false, 0, 1, 0);

  for (int kt = 0; kt < nk; ++kt) {
    int cur = kt & 1, nxt = cur ^ 1;
    asm volatile("s_waitcnt vmcnt(0)\n\ts_barrier" ::: "memory");
    const u16* Ab = lds + cur * 16384 + wm * 8192;
    const u16* Bb = lds + 32768 + cur * 16384 + (wn >> 1) * 8192 + (wn & 1) * 4096;
    bool more = (kt + 1) < nk;
#pragma unroll
    for (int kk = 0; kk < 2; ++kk) {
      int csw = ((kk * 4 + l16) ^ l7) * 8;
      bf16x8 bf[4];
#pragma unroll
      for (int j = 0; j < 4; ++j)
        bf[j] = *(const bf16x8*)&Bb[(j * 16 + l15) * 64 + csw];
#pragma unroll
      for (int frh = 0; frh < 2; ++frh) {
        bf16x8 af[4];
#pragma unroll
        for (int i = 0; i < 4; ++i)
          af[i] = *(const bf16x8*)&Ab[((frh * 4 + i) * 16 + l15) * 64 + csw];
        if (more) {
          if (kk == 0 && frh == 0) {
            stage_half(true, nxt, 0, kt + 1); stage_half(true, nxt, 1, kt + 1);
          } else if (kk == 0 && frh == 1) {
            stage_half(false, nxt, 0, kt + 1); stage_half(false, nxt, 1, kt + 1);
          }
        }
        asm volatile("s_barrier" ::: "memory");
        __builtin_amdgcn_s_setprio(1);
#pragma unroll
        for (int i = 0; i < 4; ++i)
#pragma unroll
          for (int j = 0; j < 4; ++j)
            acc[frh * 4 + i][j] = __builtin_amdgcn_mfma_f32_16x16x32_bf16(
                af[i], bf[j], acc[frh * 4 + i][j], 0, 0, 0);
        __builtin_amdgcn_s_setprio(0);
        asm volatile("s_barrier" ::: "memory");
      }
    }
  }

  int lq = l16, lr = l15;
  float* ep = (float*)((char*)lds + wid * 4608);
  long cb  = (long)b * sC + (long)s * sS;
  int row0 = (int)m0 + wm * 128;
  int colb = (int)n0 + wn * 64;
#pragma unroll
  for (int fr = 0; fr < 8; ++fr) {
#pragma unroll
    for (int j = 0; j < 4; ++j)
#pragma unroll
      for (int r = 0; r < 4; ++r)
        ep[(lq * 4 + r) * 72 + lr + j * 16] = acc[fr][j][r];
#pragma unroll
    for (int p = 0; p < 4; ++p) {
      int rl = p * 4 + lq;
      f32x4 v = *(f32x4*)&ep[rl * 72 + lr * 4];
      long off = (long)(row0 + fr * 16 + rl) * ldc + colb + lr * 4;
      if (MODE == 0) {
        u16v4 o;
#pragma unroll
        for (int t2 = 0; t2 < 4; ++t2) o[t2] = f2bf(v[t2]);
        *(u16v4*)((u16*)Cout + cb + off) = o;
      } else {
        const float* R = Res + (long)b * sRes;
        f32v4 rv = *(const f32v4*)&R[off];
        f32v4 ov;
#pragma unroll
        for (int t2 = 0; t2 < 4; ++t2) ov[t2] = v[t2] + rv[t2];
        *(f32v4*)((float*)Cout + cb + off) = ov;
      }
    }
  }
}

// ------- NT GEMM 128x128, DOUBLE-buffered + counted vmcnt (R8 style, 2 blk/CU) -------
// LDS 64KB: As0 @0, As1 @16384, Bs0 @32768, Bs1 @49152. bf16 store only.
__global__ __launch_bounds__(256) void gemm_nt(
    const u16* __restrict__ A, const u16* __restrict__ B, u16* __restrict__ Cout,
    int K, int lda, int ldb, int ldc, long sA, long sB, long sC) {
  __shared__ __align__(16) char smem_c[65536];

  int gx = gridDim.x, gy = gridDim.y;
  int nwg = gx * gy * (int)gridDim.z;
  int flat = blockIdx.x + gx * (blockIdx.y + gy * blockIdx.z);
  if ((nwg & 7) == 0) { int q = nwg >> 3; flat = (flat & 7) * q + (flat >> 3); }
  int bx = flat % gx; int tmp = flat / gx; int by = tmp % gy; int b = tmp / gy;

  long m0 = (long)bx * 128;
  long n0 = (long)by * 128;
  const u16* Ag = A + (long)b * sA;
  const u16* Bg = B + (long)b * sB;

  int tid  = threadIdx.x;
  int lane = tid & 63;
  int wid  = tid >> 6;
  int wm = wid >> 1, wn = wid & 1;

  int srow = wid * 8 + (lane >> 3);
  int scol = (lane & 7) * 8;

  auto stageA = [&](u16* Asd, int k0) {
#pragma unroll
    for (int c = 0; c < 4; ++c) {
      int row = c * 32 + srow;
      __builtin_amdgcn_global_load_lds(
          (const __attribute__((address_space(1))) void*)(Ag + (m0 + row) * lda + k0 + scol),
          (__attribute__((address_space(3))) void*)(Asd + (c * 32 + wid * 8) * 64),
          16, 0, 0);
    }
  };
  auto stageB = [&](u16* Bsd, int k0) {
#pragma unroll
    for (int c = 0; c < 4; ++c) {
      int row = c * 32 + srow;
      __builtin_amdgcn_global_load_lds(
          (const __attribute__((address_space(1))) void*)(Bg + (n0 + row) * ldb + k0 + scol),
          (__attribute__((address_space(3))) void*)(Bsd + (c * 32 + wid * 8) * 64),
          16, 0, 0);
    }
  };

  f32x4 acc[4][4] = {};
  int nk = K >> 6;

  stageA((u16*)smem_c, 0);
  stageB((u16*)(smem_c + 32768), 0);

  for (int t = 0; t < nk; ++t) {
    u16* Asc = (u16*)(smem_c + (t & 1) * 16384);
    u16* Bsc = (u16*)(smem_c + 32768 + (t & 1) * 16384);
    if (t + 1 < nk) {
      u16* Asn = (u16*)(smem_c + ((t + 1) & 1) * 16384);
      u16* Bsn = (u16*)(smem_c + 32768 + ((t + 1) & 1) * 16384);
      stageA(Asn, (t + 1) * 64);
      stageB(Bsn, (t + 1) * 64);
      asm volatile("s_waitcnt vmcnt(8)\n\ts_barrier" ::: "memory");
    } else {
      asm volatile("s_waitcnt vmcnt(0)\n\ts_barrier" ::: "memory");
    }
#pragma unroll
    for (int kk = 0; kk < 2; ++kk) {
      int kofs = kk * 32 + (lane >> 4) * 8;
      bf16x8 af[4], bfr[4];
#pragma unroll
      for (int i = 0; i < 4; ++i) {
        af[i]  = *(const bf16x8*)&Asc[(wm * 64 + i * 16 + (lane & 15)) * 64 + kofs];
        bfr[i] = *(const bf16x8*)&Bsc[(wn * 64 + i * 16 + (lane & 15)) * 64 + kofs];
      }
#pragma unroll
      for (int i = 0; i < 4; ++i)
#pragma unroll
        for (int j = 0; j < 4; ++j)
          acc[i][j] = __builtin_amdgcn_mfma_f32_16x16x32_bf16(af[i], bfr[j], acc[i][j], 0, 0, 0);
    }
    asm volatile("s_barrier" ::: "memory");
  }

  float* ep = (float*)(smem_c + wid * 4608);
  long cb  = (long)b * sC;
  int row0 = (int)m0 + wm * 64;
  int colb = (int)n0 + wn * 64;
  int lq = lane >> 4;
  int lr = lane & 15;

#pragma unroll
  for (int i = 0; i < 4; ++i) {
#pragma unroll
    for (int j = 0; j < 4; ++j)
#pragma unroll
      for (int r = 0; r < 4; ++r)
        ep[(lq * 4 + r) * 72 + lr + j * 16] = acc[i][j][r];
#pragma unroll
    for (int p = 0; p < 4; ++p) {
      int rl = p * 4 + lq;
      f32x4 v = *(f32x4*)&ep[rl * 72 + lr * 4];
      long off = (long)(row0 + i * 16 + rl) * ldc + colb + lr * 4;
      u16v4 o;
#pragma unroll
      for (int t2 = 0; t2 < 4; ++t2) o[t2] = f2bf(v[t2]);
      *(u16v4*)(Cout + cb + off) = o;
    }
  }
}

// ------------- NT GEMM 64x128 (small GEMMs only) -------------
__global__ __launch_bounds__(256) void gemm64(
    const u16* __restrict__ A, const u16* __restrict__ B, u16* __restrict__ Cout,
    int K, int lda, int ldb, int ldc, long sA, long sB, long sC) {
  __shared__ __align__(16) char smem_c[49152];

  int gx = gridDim.x, gy = gridDim.y;
  int nwg = gx * gy * (int)gridDim.z;
  int flat = blockIdx.x + gx * (blockIdx.y + gy * blockIdx.z);
  if ((nwg & 7) == 0) { int q = nwg >> 3; flat = (flat & 7) * q + (flat >> 3); }
  int bx = flat % gx; int tmp = flat / gx; int by = tmp % gy; int b = tmp / gy;

  long n0 = (long)bx * 128;
  long m0 = (long)by * 64;
  const u16* Ag = A + (long)b * sA;
  const u16* Bg = B + (long)b * sB;

  int tid  = threadIdx.x;
  int lane = tid & 63;
  int wid  = tid >> 6;
  int wm = wid >> 1, wn = wid & 1;

  int srow = wid * 8 + (lane >> 3);
  int scol = (lane & 7) * 8;

  auto stageA = [&](u16* Asd, int k0) {
#pragma unroll
    for (int c = 0; c < 2; ++c) {
      int row = c * 32 + srow;
      __builtin_amdgcn_global_load_lds(
          (const __attribute__((address_space(1))) void*)(Ag + (m0 + row) * lda + k0 + scol),
          (__attribute__((address_space(3))) void*)(Asd + (c * 32 + wid * 8) * 64),
          16, 0, 0);
    }
  };
  auto stageB = [&](u16* Bsd, int k0) {
#pragma unroll
    for (int c = 0; c < 4; ++c) {
      int row = c * 32 + srow;
      __builtin_amdgcn_global_load_lds(
          (const __attribute__((address_space(1))) void*)(Bg + (n0 + row) * ldb + k0 + scol),
          (__attribute__((address_space(3))) void*)(Bsd + (c * 32 + wid * 8) * 64),
          16, 0, 0);
    }
  };

  f32x4 acc[2][4] = {};
  int nk = K >> 6;

  stageA((u16*)smem_c, 0);
  stageB((u16*)(smem_c + 16384), 0);

  for (int t = 0; t < nk; ++t) {
    u16* Asc = (u16*)(smem_c + (t & 1) * 8192);
    u16* Bsc = (u16*)(smem_c + 16384 + (t & 1) * 16384);
    u16* Asn = (u16*)(smem_c + ((t + 1) & 1) * 8192);
    u16* Bsn = (u16*)(smem_c + 16384 + ((t + 1) & 1) * 16384);
    bool more = (t + 1) < nk;
    if (more) {
      stageA(Asn, (t + 1) * 64);
      stageB(Bsn, (t + 1) * 64);
      asm volatile("s_waitcnt vmcnt(6)\n\ts_barrier" ::: "memory");
    } else {
      asm volatile("s_waitcnt vmcnt(0)\n\ts_barrier" ::: "memory");
    }
#pragma unroll
    for (int kk = 0; kk < 2; ++kk) {
      int kofs = kk * 32 + (lane >> 4) * 8;
      bf16x8 af[2], bfr[4];
#pragma unroll
      for (int i = 0; i < 2; ++i)
        af[i]  = *(const bf16x8*)&Asc[(wm * 32 + i * 16 + (lane & 15)) * 64 + kofs];
#pragma unroll
      for (int j = 0; j < 4; ++j)
        bfr[j] = *(const bf16x8*)&Bsc[(wn * 64 + j * 16 + (lane & 15)) * 64 + kofs];
#pragma unroll
      for (int i = 0; i < 2; ++i)
#pragma unroll
        for (int j = 0; j < 4; ++j)
          acc[i][j] = __builtin_amdgcn_mfma_f32_16x16x32_bf16(af[i], bfr[j], acc[i][j], 0, 0, 0);
    }
    asm volatile("s_barrier" ::: "memory");
  }

  int lq = lane >> 4;
  int lr = lane & 15;
  float* ep = (float*)(smem_c + wid * 4608);
  long cb  = (long)b * sC;
  int row0 = (int)m0 + wm * 32;
  int colb = (int)n0 + wn * 64;
#pragma unroll
  for (int i = 0; i < 2; ++i) {
#pragma unroll
    for (int j = 0; j < 4; ++j)
#pragma unroll
      for (int r = 0; r < 4; ++r)
        ep[(lq * 4 + r) * 72 + lr + j * 16] = acc[i][j][r];
#pragma unroll
    for (int p = 0; p < 4; ++p) {
      int rl = p * 4 + lq;
      f32x4 v = *(f32x4*)&ep[rl * 72 + lr * 4];
      long off = (long)(row0 + i * 16 + rl) * ldc + colb + lr * 4;
      u16v4 o;
#pragma unroll
      for (int t2 = 0; t2 < 4; ++t2) o[t2] = f2bf(v[t2]);
      *(u16v4*)(Cout + cb + off) = o;
    }
  }
}

// ------- logits GEMM with FUSED channel softmax, f32 A (reads h directly) -------
__global__ __launch_bounds__(256, 2) void gemm_sm(
    const float* __restrict__ A,  // [32768 x 512] f32 (h)
    const u16* __restrict__ Bw,   // [512 x 512] bf16 (w_attn)
    u16* __restrict__ C) {        // [32768 x 512] bf16 attn
  __shared__ __align__(16) char smem[73728];
  u16* As = (u16*)smem;                 // [64][64]
  u16* Bs = (u16*)(smem + 8192);        // [512][64]

  int nwg = gridDim.x;
  int flat = blockIdx.x;
  if ((nwg & 7) == 0) { int q = nwg >> 3; flat = (flat & 7) * q + (flat >> 3); }
  long m0 = (long)flat * 64;

  int tid = threadIdx.x;
  int lane = tid & 63;
  int wid = tid >> 6;

  int srow = wid * 8 + (lane >> 3);
  int scol = (lane & 7) * 8;
  int arow  = tid >> 2;
  int acolb = (tid & 3) * 16;

  f32x4 acc[4][8] = {};

  for (int k0 = 0; k0 < 512; k0 += 64) {
    const float* sp = A + (m0 + arow) * 512 + k0 + acolb;
    f32v4 x0 = *(const f32v4*)sp;
    f32v4 x1 = *(const f32v4*)(sp + 4);
    f32v4 x2 = *(const f32v4*)(sp + 8);
    f32v4 x3 = *(const f32v4*)(sp + 12);
#pragma unroll
    for (int c = 0; c < 16; ++c) {
      int row = c * 32 + srow;
      __builtin_amdgcn_global_load_lds(
          (const __attribute__((address_space(1))) void*)(Bw + (long)row * 512 + k0 + scol),
          (__attribute__((address_space(3))) void*)(Bs + (c * 32 + wid * 8) * 64),
          16, 0, 0);
    }
    u16v8 o0, o1;
    o0[0] = f2bf(x0[0]); o0[1] = f2bf(x0[1]); o0[2] = f2bf(x0[2]); o0[3] = f2bf(x0[3]);
    o0[4] = f2bf(x1[0]); o0[5] = f2bf(x1[1]); o0[6] = f2bf(x1[2]); o0[7] = f2bf(x1[3]);
    o1[0] = f2bf(x2[0]); o1[1] = f2bf(x2[1]); o1[2] = f2bf(x2[2]); o1[3] = f2bf(x2[3]);
    o1[4] = f2bf(x3[0]); o1[5] = f2bf(x3[1]); o1[6] = f2bf(x3[2]); o1[7] = f2bf(x3[3]);
    *(u16v8*)&As[arow * 64 + acolb] = o0;
    *(u16v8*)&As[arow * 64 + acolb + 8] = o1;
    __syncthreads();
#pragma unroll
    for (int kk = 0; kk < 2; ++kk) {
      int kofs = kk * 32 + (lane >> 4) * 8;
      bf16x8 af[4], bfr[8];
#pragma unroll
      for (int i = 0; i < 4; ++i)
        af[i] = *(const bf16x8*)&As[(i * 16 + (lane & 15)) * 64 + kofs];
#pragma unroll
      for (int j = 0; j < 8; ++j)
        bfr[j] = *(const bf16x8*)&Bs[(wid * 128 + j * 16 + (lane & 15)) * 64 + kofs];
#pragma unroll
      for (int i = 0; i < 4; ++i)
#pragma unroll
        for (int j = 0; j < 8; ++j)
          acc[i][j] = __builtin_amdgcn_mfma_f32_16x16x32_bf16(af[i], bfr[j], acc[i][j], 0, 0, 0);
    }
    __syncthreads();
  }

  int lq = lane >> 4, lr = lane & 15;
  float* sm = (float*)smem;            // [64][4]
  float* ss = (float*)(smem + 1024);   // [64][4]

#pragma unroll
  for (int i = 0; i < 4; ++i)
#pragma unroll
    for (int r = 0; r < 4; ++r) {
      float m = acc[i][0][r];
#pragma unroll
      for (int j = 1; j < 8; ++j) m = fmaxf(m, acc[i][j][r]);
#pragma unroll
      for (int o = 1; o < 16; o <<= 1) m = fmaxf(m, __shfl_xor(m, o, 16));
      if (lr == 0) sm[(i * 16 + lq * 4 + r) * 4 + wid] = m;
    }
  __syncthreads();
  float rinv[4][4];
#pragma unroll
  for (int i = 0; i < 4; ++i)
#pragma unroll
    for (int r = 0; r < 4; ++r) {
      f32v4 g4 = *(const f32v4*)&sm[(i * 16 + lq * 4 + r) * 4];
      float gm = fmaxf(fmaxf(g4[0], g4[1]), fmaxf(g4[2], g4[3]));
      float s = 0.f;
#pragma unroll
      for (int j = 0; j < 8; ++j) {
        float e = __expf(acc[i][j][r] - gm);
        acc[i][j][r] = e;
        s += e;
      }
#pragma unroll
      for (int o = 1; o < 16; o <<= 1) s += __shfl_xor(s, o, 16);
      if (lr == 0) ss[(i * 16 + lq * 4 + r) * 4 + wid] = s;
    }
  __syncthreads();
#pragma unroll
  for (int i = 0; i < 4; ++i)
#pragma unroll
    for (int r = 0; r < 4; ++r) {
      f32v4 g4 = *(const f32v4*)&ss[(i * 16 + lq * 4 + r) * 4];
      rinv[i][r] = 1.0f / (g4[0] + g4[1] + g4[2] + g4[3]);
    }
  __syncthreads();

  float* ep = (float*)(smem + wid * 4608);
#pragma unroll
  for (int i = 0; i < 4; ++i) {
#pragma unroll
    for (int jh = 0; jh < 2; ++jh) {
#pragma unroll
      for (int j = 0; j < 4; ++j)
#pragma unroll
        for (int r = 0; r < 4; ++r)
          ep[(lq * 4 + r) * 72 + lr + j * 16] = acc[i][jh * 4 + j][r] * rinv[i][r];
#pragma unroll
      for (int p = 0; p < 4; ++p) {
        int rl = p * 4 + lq;
        f32x4 v = *(f32x4*)&ep[rl * 72 + lr * 4];
        u16v4 o;
#pragma unroll
        for (int t = 0; t < 4; ++t) o[t] = f2bf(v[t]);
        *(u16v4*)&C[(m0 + i * 16 + rl) * 512 + wid * 128 + jh * 64 + lr * 4] = o;
      }
    }
  }
}

// ---------------- host ----------------
extern "C" void kernel_launch(void* const* d_in, const int* in_sizes, int n_in,
                              void* d_out, int out_size, void* d_ws, size_t ws_size,
                              hipStream_t stream) {
  (void)in_sizes; (void)n_in; (void)out_size; (void)ws_size;
  const float* h    = (const float*)d_in[0];
  const float* hret = (const float*)d_in[1];
  const float* Wc   = (const float*)d_in[2];
  const float* Wa   = (const float*)d_in[3];
  const float* Wk   = (const float*)d_in[4];
  const float* Wv   = (const float*)d_in[5];
  const float* Wo   = (const float*)d_in[6];
  float* out = (float*)d_out;
  char*  ws  = (char*)d_ws;

  constexpr long MB = 1024 * 1024;
  // workspace: weights 0..4MB; hret_bf 4..28 (dead before Gram writes gparts);
  // gparts 4..36; attn 36..68; g_bf 68; u 72; v1 73; f2t 77; xt 84..132.
  u16*   w_cond  = (u16*)(ws + 0);
  u16*   w_attn  = (u16*)(ws + 786432);
  u16*   w_k     = (u16*)(ws + 1310720);
  u16*   w_v     = (u16*)(ws + 1835008);
  u16*   w_out   = (u16*)(ws + 2359296);
  u16*   w_vT    = (u16*)(ws + 2883584);
  u16*   hret_bf = (u16*)(ws + 4 * MB);
  u16*   gparts  = (u16*)(ws + 4 * MB);   // overlay hret_bf (dead before Gram)
  u16*   attn    = (u16*)(ws + 36 * MB);
  u16*   g_bf    = (u16*)(ws + 68 * MB);
  u16*   u_mat   = (u16*)(ws + 72 * MB);
  u16*   v1      = (u16*)(ws + 73 * MB);
  u16*   f2t     = (u16*)(ws + 77 * MB);
  u16*   xt      = (u16*)(ws + 84 * MB);

  // 1) xt[:, 0:4096] = h^T (f32 read, bf16 transposed write)
  cvt_T<<<dim3(64, 8, 8), 256, 0, stream>>>(h, xt, 2097152L, 3145728L);
  // 2) all weights in one dispatch
  prep_weights<<<640, 256, 0, stream>>>(Wc, Wa, Wk, Wv, Wo,
      w_cond, w_attn, w_k, w_v, w_vT, w_out);
  // 3) hret -> bf16 (plain layout)
  cvt_f32_bf16<<<6144, 256, 0, stream>>>(hret, hret_bf, 12582912L);

  // 4) hr^T = W_c @ hret^T == NT(w_cond, hret_bf), normal coalesced store
  //    into xt[:, 4096:6144].  M=512 (d), N=2048 (n), K=768; A shared across batches.
  gemm_nt<<<dim3(4, 16, 8), 256, 0, stream>>>(w_cond, hret_bf, xt + 4096,
      768, 768, 768, 6144, 0, 1572864L, 3145728L);

  // 5) attn = softmax(h @ W_attn^T) fused, reads h f32 directly (M=32768 flat)
  gemm_sm<<<512, 256, 0, stream>>>(h, w_attn, attn);

  // 6) Gram G = X^T X via 256^2 multi-phase kernel, split-K=8, grid 256 = 1/CU
  gemm256<0><<<dim3(2, 2, 64), 512, 0, stream>>>(xt, xt, gparts, nullptr,
      768, 6144, 6144, 512, 3145728L, 3145728L, 2097152L, 262144L, 0, 8);
  reduce8_bf16<<<1024, 256, 0, stream>>>(gparts, g_bf);

  // 7) f2^T = W_out W_v G W_k^T (G symmetric):
  gemm64<<<dim3(4, 8, 1), 256, 0, stream>>>(w_out, w_vT, u_mat,
      512, 512, 512, 512, 0, 0, 0);
  gemm64<<<dim3(4, 8, 8), 256, 0, stream>>>(u_mat, g_bf, v1,
      512, 512, 512, 512, 0, 262144L, 262144L);
  gemm64<<<dim3(4, 8, 8), 256, 0, stream>>>(v1, w_k, f2t,
      512, 512, 512, 512, 262144L, 0, 262144L);

  // 8) out = h + attn @ f2  (256^2 multi-phase, fused residual, grid 256 = 1/CU)
  gemm256<1><<<dim3(16, 2, 8), 512, 0, stream>>>(attn, f2t, out, h,
      512, 512, 512, 512, 2097152L, 262144L, 2097152L, 0, 2097152L, 1);
}

// Round 12
// 191.719 us; speedup vs baseline: 1.2428x; 1.0285x over previous
//
#include <hip/hip_runtime.h>
#include <hip/hip_bf16.h>

// Problem: B=8, N=4096, M=2048, IN=512, D=512, CTX=768
// out = h + attn @ f2,  attn = softmax(h W_a^T),  f2^T = W_out W_v G W_k^T,
// G = X^T X (symmetric), X = [h; h_retrieved W_c^T],  hr^T = W_c hret^T.

typedef unsigned short u16;
typedef __bf16 bf16x8 __attribute__((ext_vector_type(8)));
typedef float  f32x4  __attribute__((ext_vector_type(4)));
typedef float  f32v4  __attribute__((ext_vector_type(4)));
typedef u16    u16v4  __attribute__((ext_vector_type(4)));
typedef u16    u16v8  __attribute__((ext_vector_type(8)));

__device__ __forceinline__ u16 f2bf(float f) {
  unsigned u = __builtin_bit_cast(unsigned, f);
  u = u + 0x7FFFu + ((u >> 16) & 1u);   // RNE; inputs are finite
  return (u16)(u >> 16);
}
__device__ __forceinline__ float bf2f(u16 s) {
  return __builtin_bit_cast(float, (unsigned)s << 16);
}

// ---------------- elementwise f32 -> bf16 ----------------
__global__ __launch_bounds__(256) void cvt_f32_bf16(const float* __restrict__ in,
                                                    u16* __restrict__ out, long n) {
  long i = (((long)blockIdx.x * 256) + threadIdx.x) * 8;
  if (i >= n) return;
  f32v4 a = *(const f32v4*)(in + i);
  f32v4 b = *(const f32v4*)(in + i + 4);
  u16v8 o;
  o[0] = f2bf(a[0]); o[1] = f2bf(a[1]); o[2] = f2bf(a[2]); o[3] = f2bf(a[3]);
  o[4] = f2bf(b[0]); o[5] = f2bf(b[1]); o[6] = f2bf(b[2]); o[7] = f2bf(b[3]);
  *(u16v8*)(out + i) = o;
}

// ------- f32 -> bf16 transpose: xt[b][c][r] = bf16(h[b][r][c]) -------
__global__ __launch_bounds__(256) void cvt_T(const float* __restrict__ src,
                                             u16* __restrict__ dstT,
                                             long src_bs, long dstT_bs) {
  __shared__ u16 tile[64][72];
  long bz = blockIdx.z;
  const float* S = src + bz * src_bs;
  u16* DT = dstT + bz * dstT_bs;
  int r0 = blockIdx.x * 64;
  int c0 = blockIdx.y * 64;
  int t  = threadIdx.x;
  int tr = t >> 2;
  int tc = (t & 3) * 16;
  const float* sp = &S[(long)(r0 + tr) * 512 + c0 + tc];
#pragma unroll
  for (int q = 0; q < 2; ++q) {
    f32v4 a = *(const f32v4*)(sp + q * 8);
    f32v4 b = *(const f32v4*)(sp + q * 8 + 4);
    u16v8 o;
    o[0] = f2bf(a[0]); o[1] = f2bf(a[1]); o[2] = f2bf(a[2]); o[3] = f2bf(a[3]);
    o[4] = f2bf(b[0]); o[5] = f2bf(b[1]); o[6] = f2bf(b[2]); o[7] = f2bf(b[3]);
    *(u16v8*)&tile[tr][tc + q * 8] = o;
  }
  __syncthreads();
  int tr2 = t >> 3;
  int tc2 = (t & 7) * 8;
#pragma unroll
  for (int it = 0; it < 2; ++it) {
    int cr = it * 32 + tr2;
    u16v8 o;
#pragma unroll
    for (int j = 0; j < 8; ++j) o[j] = tile[tc2 + j][cr];
    *(u16v8*)&DT[(long)(c0 + cr) * 6144 + r0 + tc2] = o;
  }
}

// ------- all weight prep in ONE dispatch -------
__global__ __launch_bounds__(256) void prep_weights(
    const float* __restrict__ Wc, const float* __restrict__ Wa,
    const float* __restrict__ Wk, const float* __restrict__ Wv,
    const float* __restrict__ Wo,
    u16* __restrict__ wc, u16* __restrict__ wa, u16* __restrict__ wk,
    u16* __restrict__ wv, u16* __restrict__ wvT, u16* __restrict__ wo) {
  __shared__ u16 tile[64][72];
  int bx = blockIdx.x;
  int t = threadIdx.x;
  if (bx < 576) {
    const float* src; u16* dst; long base;
    if (bx < 192)      { src = Wc; dst = wc; base = (long)bx * 2048; }
    else if (bx < 320) { src = Wa; dst = wa; base = (long)(bx - 192) * 2048; }
    else if (bx < 448) { src = Wk; dst = wk; base = (long)(bx - 320) * 2048; }
    else               { src = Wo; dst = wo; base = (long)(bx - 448) * 2048; }
    long i = base + (long)t * 8;
    f32v4 a = *(const f32v4*)(src + i);
    f32v4 b = *(const f32v4*)(src + i + 4);
    u16v8 o;
    o[0] = f2bf(a[0]); o[1] = f2bf(a[1]); o[2] = f2bf(a[2]); o[3] = f2bf(a[3]);
    o[4] = f2bf(b[0]); o[5] = f2bf(b[1]); o[6] = f2bf(b[2]); o[7] = f2bf(b[3]);
    *(u16v8*)(dst + i) = o;
  } else {
    int b2 = bx - 576;
    int r0 = (b2 >> 3) * 64, c0 = (b2 & 7) * 64;
    int tr = t >> 2, tc = (t & 3) * 16;
    const float* sp = &Wv[(long)(r0 + tr) * 512 + c0 + tc];
#pragma unroll
    for (int q = 0; q < 2; ++q) {
      f32v4 a = *(const f32v4*)(sp + q * 8);
      f32v4 b = *(const f32v4*)(sp + q * 8 + 4);
      u16v8 o;
      o[0] = f2bf(a[0]); o[1] = f2bf(a[1]); o[2] = f2bf(a[2]); o[3] = f2bf(a[3]);
      o[4] = f2bf(b[0]); o[5] = f2bf(b[1]); o[6] = f2bf(b[2]); o[7] = f2bf(b[3]);
      *(u16v8*)&wv[(long)(r0 + tr) * 512 + c0 + tc + q * 8] = o;
      *(u16v8*)&tile[tr][tc + q * 8] = o;
    }
    __syncthreads();
    int tr2 = t >> 3, tc2 = (t & 7) * 8;
#pragma unroll
    for (int it = 0; it < 2; ++it) {
      int cr = it * 32 + tr2;
      u16v8 o;
#pragma unroll
      for (int j = 0; j < 8; ++j) o[j] = tile[tc2 + j][cr];
      *(u16v8*)&wvT[(long)(c0 + cr) * 512 + r0 + tc2] = o;
    }
  }
}

// -------- reduce 8 split-K bf16 slices -> bf16 (per batch 512x512) --------
__global__ __launch_bounds__(256) void reduce8_bf16(const u16* __restrict__ parts,
                                                    u16* __restrict__ out) {
  long i = (((long)blockIdx.x * 256) + threadIdx.x) * 8;
  long b = i >> 18;
  long r = i & 262143;
  const u16* p = parts + b * 2097152 + r;
  float acc[8] = {};
#pragma unroll
  for (int s = 0; s < 8; ++s) {
    u16v8 v = *(const u16v8*)(p + (long)s * 262144);
#pragma unroll
    for (int j = 0; j < 8; ++j) acc[j] += bf2f(v[j]);
  }
  u16v8 o;
#pragma unroll
  for (int j = 0; j < 8; ++j) o[j] = f2bf(acc[j]);
  *(u16v8*)(out + i) = o;
}

// ============ 256x256 multi-phase GEMM (R9 version, measured) ============
template <int MODE>
__global__ __launch_bounds__(512, 2) void gemm256(
    const u16* __restrict__ A, const u16* __restrict__ B, void* __restrict__ Cout,
    const float* __restrict__ Res, int K, int lda, int ldb, int ldc,
    long sA, long sB, long sC, long sS, long sRes, int kslices) {
  __shared__ __align__(16) u16 lds[65536];   // 128 KB

  int gx = gridDim.x, gy = gridDim.y;
  int nwg = gx * gy * (int)gridDim.z;
  int flat = blockIdx.x + gx * (blockIdx.y + gy * blockIdx.z);
  if ((nwg & 7) == 0) { int q = nwg >> 3; flat = (flat & 7) * q + (flat >> 3); }
  int bx = flat % gx; int tmp = flat / gx; int by = tmp % gy; int z = tmp / gy;
  int b = z / kslices;
  int s = z - b * kslices;

  long m0 = (long)bx * 256;
  long n0 = (long)by * 256;
  const u16* Ag = A + (long)b * sA + (long)s * K;
  const u16* Bg = B + (long)b * sB + (long)s * K;

  int tid  = threadIdx.x;
  int lane = tid & 63;
  int wid  = tid >> 6;        // 0..7
  int wm = wid >> 2;          // 0..1
  int wn = wid & 3;           // 0..3
  int l15 = lane & 15, l16 = lane >> 4, l7 = lane & 7;

  auto stage_half = [&](bool isA, int buf, int h, int ktile) {
    const u16* G = isA ? Ag : Bg;
    long rb = (isA ? m0 : n0) + h * 128;
    int ldg = isA ? lda : ldb;
    u16* base = lds + (isA ? 0 : 32768) + buf * 16384 + h * 8192;
    int row_lo = wid * 8 + (lane >> 3);
    int ce = ((lane & 7) ^ ((lane >> 3) & 7)) * 8;
#pragma unroll
    for (int q = 0; q < 2; ++q) {
      const u16* src = G + (rb + q * 64 + row_lo) * (long)ldg + ktile * 64 + ce;
      u16* dst = base + (q * 512 + wid * 64) * 8;
      __builtin_amdgcn_global_load_lds(
          (const __attribute__((address_space(1))) void*)src,
          (__attribute__((address_space(3))) void*)dst, 16, 0, 0);
    }
  };

  f32x4 acc[8][4] = {};
  int nk = K >> 6;

  stage_half(true,  0, 0, 0); stage_half(true,  0, 1, 0);
  stage_half(false, 0, 0, 0); stage_half(false, 0, 1, 0);

  for (int kt = 0; kt < nk; ++kt) {
    int cur = kt & 1, nxt = cur ^ 1;
    asm volatile("s_waitcnt vmcnt(0)\n\ts_barrier" ::: "memory");
    const u16* Ab = lds + cur * 16384 + wm * 8192;
    const u16* Bb = lds + 32768 + cur * 16384 + (wn >> 1) * 8192 + (wn & 1) * 4096;
    bool more = (kt + 1) < nk;
#pragma unroll
    for (int kk = 0; kk < 2; ++kk) {
      int csw = ((kk * 4 + l16) ^ l7) * 8;
      bf16x8 bf[4];
#pragma unroll
      for (int j = 0; j < 4; ++j)
        bf[j] = *(const bf16x8*)&Bb[(j * 16 + l15) * 64 + csw];
#pragma unroll
      for (int frh = 0; frh < 2; ++frh) {
        bf16x8 af[4];
#pragma unroll
        for (int i = 0; i < 4; ++i)
          af[i] = *(const bf16x8*)&Ab[((frh * 4 + i) * 16 + l15) * 64 + csw];
        if (more) {
          if (kk == 0 && frh == 0) {
            stage_half(true, nxt, 0, kt + 1); stage_half(true, nxt, 1, kt + 1);
          } else if (kk == 0 && frh == 1) {
            stage_half(false, nxt, 0, kt + 1); stage_half(false, nxt, 1, kt + 1);
          }
        }
        asm volatile("s_barrier" ::: "memory");
        __builtin_amdgcn_s_setprio(1);
#pragma unroll
        for (int i = 0; i < 4; ++i)
#pragma unroll
          for (int j = 0; j < 4; ++j)
            acc[frh * 4 + i][j] = __builtin_amdgcn_mfma_f32_16x16x32_bf16(
                af[i], bf[j], acc[frh * 4 + i][j], 0, 0, 0);
        __builtin_amdgcn_s_setprio(0);
        asm volatile("s_barrier" ::: "memory");
      }
    }
  }

  int lq = l16, lr = l15;
  float* ep = (float*)((char*)lds + wid * 4608);
  long cb  = (long)b * sC + (long)s * sS;
  int row0 = (int)m0 + wm * 128;
  int colb = (int)n0 + wn * 64;
#pragma unroll
  for (int fr = 0; fr < 8; ++fr) {
#pragma unroll
    for (int j = 0; j < 4; ++j)
#pragma unroll
      for (int r = 0; r < 4; ++r)
        ep[(lq * 4 + r) * 72 + lr + j * 16] = acc[fr][j][r];
#pragma unroll
    for (int p = 0; p < 4; ++p) {
      int rl = p * 4 + lq;
      f32x4 v = *(f32x4*)&ep[rl * 72 + lr * 4];
      long off = (long)(row0 + fr * 16 + rl) * ldc + colb + lr * 4;
      if (MODE == 0) {
        u16v4 o;
#pragma unroll
        for (int t2 = 0; t2 < 4; ++t2) o[t2] = f2bf(v[t2]);
        *(u16v4*)((u16*)Cout + cb + off) = o;
      } else {
        const float* R = Res + (long)b * sRes;
        f32v4 rv = *(const f32v4*)&R[off];
        f32v4 ov;
#pragma unroll
        for (int t2 = 0; t2 < 4; ++t2) ov[t2] = v[t2] + rv[t2];
        *(f32v4*)((float*)Cout + cb + off) = ov;
      }
    }
  }
}

// ------- NT GEMM 128x128, DOUBLE-buffered + counted vmcnt (2 blk/CU) -------
__global__ __launch_bounds__(256) void gemm_nt(
    const u16* __restrict__ A, const u16* __restrict__ B, u16* __restrict__ Cout,
    int K, int lda, int ldb, int ldc, long sA, long sB, long sC) {
  __shared__ __align__(16) char smem_c[65536];

  int gx = gridDim.x, gy = gridDim.y;
  int nwg = gx * gy * (int)gridDim.z;
  int flat = blockIdx.x + gx * (blockIdx.y + gy * blockIdx.z);
  if ((nwg & 7) == 0) { int q = nwg >> 3; flat = (flat & 7) * q + (flat >> 3); }
  int bx = flat % gx; int tmp = flat / gx; int by = tmp % gy; int b = tmp / gy;

  long m0 = (long)bx * 128;
  long n0 = (long)by * 128;
  const u16* Ag = A + (long)b * sA;
  const u16* Bg = B + (long)b * sB;

  int tid  = threadIdx.x;
  int lane = tid & 63;
  int wid  = tid >> 6;
  int wm = wid >> 1, wn = wid & 1;

  int srow = wid * 8 + (lane >> 3);
  int scol = (lane & 7) * 8;

  auto stageA = [&](u16* Asd, int k0) {
#pragma unroll
    for (int c = 0; c < 4; ++c) {
      int row = c * 32 + srow;
      __builtin_amdgcn_global_load_lds(
          (const __attribute__((address_space(1))) void*)(Ag + (m0 + row) * lda + k0 + scol),
          (__attribute__((address_space(3))) void*)(Asd + (c * 32 + wid * 8) * 64),
          16, 0, 0);
    }
  };
  auto stageB = [&](u16* Bsd, int k0) {
#pragma unroll
    for (int c = 0; c < 4; ++c) {
      int row = c * 32 + srow;
      __builtin_amdgcn_global_load_lds(
          (const __attribute__((address_space(1))) void*)(Bg + (n0 + row) * ldb + k0 + scol),
          (__attribute__((address_space(3))) void*)(Bsd + (c * 32 + wid * 8) * 64),
          16, 0, 0);
    }
  };

  f32x4 acc[4][4] = {};
  int nk = K >> 6;

  stageA((u16*)smem_c, 0);
  stageB((u16*)(smem_c + 32768), 0);

  for (int t = 0; t < nk; ++t) {
    u16* Asc = (u16*)(smem_c + (t & 1) * 16384);
    u16* Bsc = (u16*)(smem_c + 32768 + (t & 1) * 16384);
    if (t + 1 < nk) {
      u16* Asn = (u16*)(smem_c + ((t + 1) & 1) * 16384);
      u16* Bsn = (u16*)(smem_c + 32768 + ((t + 1) & 1) * 16384);
      stageA(Asn, (t + 1) * 64);
      stageB(Bsn, (t + 1) * 64);
      asm volatile("s_waitcnt vmcnt(8)\n\ts_barrier" ::: "memory");
    } else {
      asm volatile("s_waitcnt vmcnt(0)\n\ts_barrier" ::: "memory");
    }
#pragma unroll
    for (int kk = 0; kk < 2; ++kk) {
      int kofs = kk * 32 + (lane >> 4) * 8;
      bf16x8 af[4], bfr[4];
#pragma unroll
      for (int i = 0; i < 4; ++i) {
        af[i]  = *(const bf16x8*)&Asc[(wm * 64 + i * 16 + (lane & 15)) * 64 + kofs];
        bfr[i] = *(const bf16x8*)&Bsc[(wn * 64 + i * 16 + (lane & 15)) * 64 + kofs];
      }
#pragma unroll
      for (int i = 0; i < 4; ++i)
#pragma unroll
        for (int j = 0; j < 4; ++j)
          acc[i][j] = __builtin_amdgcn_mfma_f32_16x16x32_bf16(af[i], bfr[j], acc[i][j], 0, 0, 0);
    }
    asm volatile("s_barrier" ::: "memory");
  }

  float* ep = (float*)(smem_c + wid * 4608);
  long cb  = (long)b * sC;
  int row0 = (int)m0 + wm * 64;
  int colb = (int)n0 + wn * 64;
  int lq = lane >> 4;
  int lr = lane & 15;

#pragma unroll
  for (int i = 0; i < 4; ++i) {
#pragma unroll
    for (int j = 0; j < 4; ++j)
#pragma unroll
      for (int r = 0; r < 4; ++r)
        ep[(lq * 4 + r) * 72 + lr + j * 16] = acc[i][j][r];
#pragma unroll
    for (int p = 0; p < 4; ++p) {
      int rl = p * 4 + lq;
      f32x4 v = *(f32x4*)&ep[rl * 72 + lr * 4];
      long off = (long)(row0 + i * 16 + rl) * ldc + colb + lr * 4;
      u16v4 o;
#pragma unroll
      for (int t2 = 0; t2 < 4; ++t2) o[t2] = f2bf(v[t2]);
      *(u16v4*)(Cout + cb + off) = o;
    }
  }
}

// ------------- NT GEMM 64x128 (small GEMMs only) -------------
__global__ __launch_bounds__(256) void gemm64(
    const u16* __restrict__ A, const u16* __restrict__ B, u16* __restrict__ Cout,
    int K, int lda, int ldb, int ldc, long sA, long sB, long sC) {
  __shared__ __align__(16) char smem_c[49152];

  int gx = gridDim.x, gy = gridDim.y;
  int nwg = gx * gy * (int)gridDim.z;
  int flat = blockIdx.x + gx * (blockIdx.y + gy * blockIdx.z);
  if ((nwg & 7) == 0) { int q = nwg >> 3; flat = (flat & 7) * q + (flat >> 3); }
  int bx = flat % gx; int tmp = flat / gx; int by = tmp % gy; int b = tmp / gy;

  long n0 = (long)bx * 128;
  long m0 = (long)by * 64;
  const u16* Ag = A + (long)b * sA;
  const u16* Bg = B + (long)b * sB;

  int tid  = threadIdx.x;
  int lane = tid & 63;
  int wid  = tid >> 6;
  int wm = wid >> 1, wn = wid & 1;

  int srow = wid * 8 + (lane >> 3);
  int scol = (lane & 7) * 8;

  auto stageA = [&](u16* Asd, int k0) {
#pragma unroll
    for (int c = 0; c < 2; ++c) {
      int row = c * 32 + srow;
      __builtin_amdgcn_global_load_lds(
          (const __attribute__((address_space(1))) void*)(Ag + (m0 + row) * lda + k0 + scol),
          (__attribute__((address_space(3))) void*)(Asd + (c * 32 + wid * 8) * 64),
          16, 0, 0);
    }
  };
  auto stageB = [&](u16* Bsd, int k0) {
#pragma unroll
    for (int c = 0; c < 4; ++c) {
      int row = c * 32 + srow;
      __builtin_amdgcn_global_load_lds(
          (const __attribute__((address_space(1))) void*)(Bg + (n0 + row) * ldb + k0 + scol),
          (__attribute__((address_space(3))) void*)(Bsd + (c * 32 + wid * 8) * 64),
          16, 0, 0);
    }
  };

  f32x4 acc[2][4] = {};
  int nk = K >> 6;

  stageA((u16*)smem_c, 0);
  stageB((u16*)(smem_c + 16384), 0);

  for (int t = 0; t < nk; ++t) {
    u16* Asc = (u16*)(smem_c + (t & 1) * 8192);
    u16* Bsc = (u16*)(smem_c + 16384 + (t & 1) * 16384);
    u16* Asn = (u16*)(smem_c + ((t + 1) & 1) * 8192);
    u16* Bsn = (u16*)(smem_c + 16384 + ((t + 1) & 1) * 16384);
    bool more = (t + 1) < nk;
    if (more) {
      stageA(Asn, (t + 1) * 64);
      stageB(Bsn, (t + 1) * 64);
      asm volatile("s_waitcnt vmcnt(6)\n\ts_barrier" ::: "memory");
    } else {
      asm volatile("s_waitcnt vmcnt(0)\n\ts_barrier" ::: "memory");
    }
#pragma unroll
    for (int kk = 0; kk < 2; ++kk) {
      int kofs = kk * 32 + (lane >> 4) * 8;
      bf16x8 af[2], bfr[4];
#pragma unroll
      for (int i = 0; i < 2; ++i)
        af[i]  = *(const bf16x8*)&Asc[(wm * 32 + i * 16 + (lane & 15)) * 64 + kofs];
#pragma unroll
      for (int j = 0; j < 4; ++j)
        bfr[j] = *(const bf16x8*)&Bsc[(wn * 64 + j * 16 + (lane & 15)) * 64 + kofs];
#pragma unroll
      for (int i = 0; i < 2; ++i)
#pragma unroll
        for (int j = 0; j < 4; ++j)
          acc[i][j] = __builtin_amdgcn_mfma_f32_16x16x32_bf16(af[i], bfr[j], acc[i][j], 0, 0, 0);
    }
    asm volatile("s_barrier" ::: "memory");
  }

  int lq = lane >> 4;
  int lr = lane & 15;
  float* ep = (float*)(smem_c + wid * 4608);
  long cb  = (long)b * sC;
  int row0 = (int)m0 + wm * 32;
  int colb = (int)n0 + wn * 64;
#pragma unroll
  for (int i = 0; i < 2; ++i) {
#pragma unroll
    for (int j = 0; j < 4; ++j)
#pragma unroll
      for (int r = 0; r < 4; ++r)
        ep[(lq * 4 + r) * 72 + lr + j * 16] = acc[i][j][r];
#pragma unroll
    for (int p = 0; p < 4; ++p) {
      int rl = p * 4 + lq;
      f32x4 v = *(f32x4*)&ep[rl * 72 + lr * 4];
      long off = (long)(row0 + i * 16 + rl) * ldc + colb + lr * 4;
      u16v4 o;
#pragma unroll
      for (int t2 = 0; t2 < 4; ++t2) o[t2] = f2bf(v[t2]);
      *(u16v4*)(Cout + cb + off) = o;
    }
  }
}

// ------- logits GEMM + FUSED channel softmax, dbuf BK=32 + counted vmcnt -------
// A = h f32 (reg-staged convert, write-late); B = w_attn (global_load_lds).
// LDS 72KB: As[2] 4KB each @0/@4096; Bs[2] 32KB each @8192/@40960. 2 blk/CU.
// Per step: {loadA(t+1) 2 VMEM; stageB(t+1) 8 VMEM; vmcnt(10)+bar;
//            12 ds_read + 32 MFMA; cvtA(t+1) ds_write; lgkmcnt(0)+bar}.
__global__ __launch_bounds__(256, 2) void gemm_sm(
    const float* __restrict__ A,  // [32768 x 512] f32 (h)
    const u16* __restrict__ Bw,   // [512 x 512] bf16 (w_attn)
    u16* __restrict__ C) {        // [32768 x 512] bf16 attn
  __shared__ __align__(16) char smem[73728];

  int nwg = gridDim.x;
  int flat = blockIdx.x;
  if ((nwg & 7) == 0) { int q = nwg >> 3; flat = (flat & 7) * q + (flat >> 3); }
  long m0 = (long)flat * 64;

  int tid = threadIdx.x;
  int lane = tid & 63;
  int wid = tid >> 6;
  int l15 = lane & 15, l16 = lane >> 4;

  int brow = wid * 16 + (lane >> 2);   // B stage row within 64-row block
  int bcol = (lane & 3) * 8;           // B stage col (elems, 16B)
  int arow = tid >> 2;                 // 0..63
  int acol = (tid & 3) * 8;            // A col (f32 elems, 8/thread)

  auto stageB = [&](int buf, int k0) {
    u16* Bd = (u16*)(smem + 8192 + buf * 32768);
#pragma unroll
    for (int c = 0; c < 8; ++c) {
      int row = c * 64 + brow;
      __builtin_amdgcn_global_load_lds(
          (const __attribute__((address_space(1))) void*)(Bw + (long)row * 512 + k0 + bcol),
          (__attribute__((address_space(3))) void*)(Bd + (c * 64 + wid * 16) * 32),
          16, 0, 0);
    }
  };

  f32v4 xa, xb;
  auto loadA = [&](int k0) {
    const float* sp = A + (m0 + arow) * 512 + k0 + acol;
    xa = *(const f32v4*)sp;
    xb = *(const f32v4*)(sp + 4);
  };
  auto cvtA = [&](int buf) {
    u16* Ad = (u16*)(smem + buf * 4096);
    u16v8 o;
    o[0] = f2bf(xa[0]); o[1] = f2bf(xa[1]); o[2] = f2bf(xa[2]); o[3] = f2bf(xa[3]);
    o[4] = f2bf(xb[0]); o[5] = f2bf(xb[1]); o[6] = f2bf(xb[2]); o[7] = f2bf(xb[3]);
    *(u16v8*)&Ad[arow * 32 + acol] = o;
  };

  f32x4 acc[4][8] = {};

  // prologue: tile 0
  loadA(0); cvtA(0);
  stageB(0, 0);
  asm volatile("s_waitcnt lgkmcnt(0)" ::: "memory");

  for (int t = 0; t < 16; ++t) {
    bool more = (t + 1) < 16;
    if (more) {
      loadA((t + 1) * 32);                 // 2 VMEM to regs
      stageB((t + 1) & 1, (t + 1) * 32);   // 8 VMEM to LDS
      asm volatile("s_waitcnt vmcnt(10)\n\ts_barrier" ::: "memory");
    } else {
      asm volatile("s_waitcnt vmcnt(0)\n\ts_barrier" ::: "memory");
    }
    const u16* As = (const u16*)(smem + (t & 1) * 4096);
    const u16* Bs = (const u16*)(smem + 8192 + (t & 1) * 32768);
    bf16x8 af[4], bfr[8];
#pragma unroll
    for (int i = 0; i < 4; ++i)
      af[i] = *(const bf16x8*)&As[(i * 16 + l15) * 32 + l16 * 8];
#pragma unroll
    for (int j = 0; j < 8; ++j)
      bfr[j] = *(const bf16x8*)&Bs[(wid * 128 + j * 16 + l15) * 32 + l16 * 8];
#pragma unroll
    for (int i = 0; i < 4; ++i)
#pragma unroll
      for (int j = 0; j < 8; ++j)
        acc[i][j] = __builtin_amdgcn_mfma_f32_16x16x32_bf16(af[i], bfr[j], acc[i][j], 0, 0, 0);
    if (more) cvtA((t + 1) & 1);
    asm volatile("s_waitcnt lgkmcnt(0)\n\ts_barrier" ::: "memory");
  }

  int lq = l16, lr = l15;
  float* sm = (float*)smem;            // [64][4]
  float* ss = (float*)(smem + 1024);   // [64][4]

#pragma unroll
  for (int i = 0; i < 4; ++i)
#pragma unroll
    for (int r = 0; r < 4; ++r) {
      float m = acc[i][0][r];
#pragma unroll
      for (int j = 1; j < 8; ++j) m = fmaxf(m, acc[i][j][r]);
#pragma unroll
      for (int o = 1; o < 16; o <<= 1) m = fmaxf(m, __shfl_xor(m, o, 16));
      if (lr == 0) sm[(i * 16 + lq * 4 + r) * 4 + wid] = m;
    }
  __syncthreads();
  float rinv[4][4];
#pragma unroll
  for (int i = 0; i < 4; ++i)
#pragma unroll
    for (int r = 0; r < 4; ++r) {
      f32v4 g4 = *(const f32v4*)&sm[(i * 16 + lq * 4 + r) * 4];
      float gm = fmaxf(fmaxf(g4[0], g4[1]), fmaxf(g4[2], g4[3]));
      float s = 0.f;
#pragma unroll
      for (int j = 0; j < 8; ++j) {
        float e = __expf(acc[i][j][r] - gm);
        acc[i][j][r] = e;
        s += e;
      }
#pragma unroll
      for (int o = 1; o < 16; o <<= 1) s += __shfl_xor(s, o, 16);
      if (lr == 0) ss[(i * 16 + lq * 4 + r) * 4 + wid] = s;
    }
  __syncthreads();
#pragma unroll
  for (int i = 0; i < 4; ++i)
#pragma unroll
    for (int r = 0; r < 4; ++r) {
      f32v4 g4 = *(const f32v4*)&ss[(i * 16 + lq * 4 + r) * 4];
      rinv[i][r] = 1.0f / (g4[0] + g4[1] + g4[2] + g4[3]);
    }
  __syncthreads();

  float* ep = (float*)(smem + wid * 4608);
#pragma unroll
  for (int i = 0; i < 4; ++i) {
#pragma unroll
    for (int jh = 0; jh < 2; ++jh) {
#pragma unroll
      for (int j = 0; j < 4; ++j)
#pragma unroll
        for (int r = 0; r < 4; ++r)
          ep[(lq * 4 + r) * 72 + lr + j * 16] = acc[i][jh * 4 + j][r] * rinv[i][r];
#pragma unroll
      for (int p = 0; p < 4; ++p) {
        int rl = p * 4 + lq;
        f32x4 v = *(f32x4*)&ep[rl * 72 + lr * 4];
        u16v4 o;
#pragma unroll
        for (int t = 0; t < 4; ++t) o[t] = f2bf(v[t]);
        *(u16v4*)&C[(m0 + i * 16 + rl) * 512 + wid * 128 + jh * 64 + lr * 4] = o;
      }
    }
  }
}

// ---------------- host ----------------
extern "C" void kernel_launch(void* const* d_in, const int* in_sizes, int n_in,
                              void* d_out, int out_size, void* d_ws, size_t ws_size,
                              hipStream_t stream) {
  (void)in_sizes; (void)n_in; (void)out_size; (void)ws_size;
  const float* h    = (const float*)d_in[0];
  const float* hret = (const float*)d_in[1];
  const float* Wc   = (const float*)d_in[2];
  const float* Wa   = (const float*)d_in[3];
  const float* Wk   = (const float*)d_in[4];
  const float* Wv   = (const float*)d_in[5];
  const float* Wo   = (const float*)d_in[6];
  float* out = (float*)d_out;
  char*  ws  = (char*)d_ws;

  constexpr long MB = 1024 * 1024;
  u16*   w_cond  = (u16*)(ws + 0);
  u16*   w_attn  = (u16*)(ws + 786432);
  u16*   w_k     = (u16*)(ws + 1310720);
  u16*   w_v     = (u16*)(ws + 1835008);
  u16*   w_out   = (u16*)(ws + 2359296);
  u16*   w_vT    = (u16*)(ws + 2883584);
  u16*   hret_bf = (u16*)(ws + 4 * MB);
  u16*   gparts  = (u16*)(ws + 4 * MB);   // overlay hret_bf (dead before Gram)
  u16*   attn    = (u16*)(ws + 36 * MB);
  u16*   g_bf    = (u16*)(ws + 68 * MB);
  u16*   u_mat   = (u16*)(ws + 72 * MB);
  u16*   v1      = (u16*)(ws + 73 * MB);
  u16*   f2t     = (u16*)(ws + 77 * MB);
  u16*   xt      = (u16*)(ws + 84 * MB);

  // 1) xt[:, 0:4096] = h^T (f32 read, bf16 transposed write)
  cvt_T<<<dim3(64, 8, 8), 256, 0, stream>>>(h, xt, 2097152L, 3145728L);
  // 2) all weights in one dispatch
  prep_weights<<<640, 256, 0, stream>>>(Wc, Wa, Wk, Wv, Wo,
      w_cond, w_attn, w_k, w_v, w_vT, w_out);
  // 3) hret -> bf16 (plain layout)
  cvt_f32_bf16<<<6144, 256, 0, stream>>>(hret, hret_bf, 12582912L);

  // 4) hr^T = W_c @ hret^T == NT(w_cond, hret_bf), normal coalesced store
  gemm_nt<<<dim3(4, 16, 8), 256, 0, stream>>>(w_cond, hret_bf, xt + 4096,
      768, 768, 768, 6144, 0, 1572864L, 3145728L);

  // 5) attn = softmax(h @ W_attn^T) fused (dbuf BK=32, reads h f32 directly)
  gemm_sm<<<512, 256, 0, stream>>>(h, w_attn, attn);

  // 6) Gram G = X^T X via 256^2 multi-phase kernel, split-K=8, grid 256 = 1/CU
  gemm256<0><<<dim3(2, 2, 64), 512, 0, stream>>>(xt, xt, gparts, nullptr,
      768, 6144, 6144, 512, 3145728L, 3145728L, 2097152L, 262144L, 0, 8);
  reduce8_bf16<<<1024, 256, 0, stream>>>(gparts, g_bf);

  // 7) f2^T = W_out W_v G W_k^T (G symmetric):
  gemm64<<<dim3(4, 8, 1), 256, 0, stream>>>(w_out, w_vT, u_mat,
      512, 512, 512, 512, 0, 0, 0);
  gemm64<<<dim3(4, 8, 8), 256, 0, stream>>>(u_mat, g_bf, v1,
      512, 512, 512, 512, 0, 262144L, 262144L);
  gemm64<<<dim3(4, 8, 8), 256, 0, stream>>>(v1, w_k, f2t,
      512, 512, 512, 512, 262144L, 0, 262144L);

  // 8) out = h + attn @ f2  (256^2 multi-phase, fused residual, grid 256 = 1/CU)
  gemm256<1><<<dim3(16, 2, 8), 512, 0, stream>>>(attn, f2t, out, h,
      512, 512, 512, 512, 2097152L, 262144L, 2097152L, 0, 2097152L, 1);
}